// Round 3
// baseline (515.286 us; speedup 1.0000x reference)
//
#include <hip/hip_runtime.h>
#include <hip/hip_cooperative_groups.h>
#include <hip/hip_bf16.h>
#include <math.h>

namespace cg = cooperative_groups;

// Problem constants
#define BB 8
#define LL 128
#define DD 512
#define EE 64
#define HH 8
#define CC 64        // D/H
#define SLOPE 0.2f
#define EPS 1e-5f

#define ES 72      // lds_e row stride (ushort)
#define ETS 138    // lds_eT/p_bf row stride
#define NPACK 1120 // pack virtual blocks

typedef short bf16x8v __attribute__((ext_vector_type(8)));
typedef float f32x4v __attribute__((ext_vector_type(4)));

static __device__ __forceinline__ unsigned short f2bf(float f) {
    union { float f; unsigned u; } v; v.f = f;
    unsigned r = v.u + 0x7FFFu + ((v.u >> 16) & 1u);   // RNE
    return (unsigned short)(r >> 16);
}

static __device__ __forceinline__ bf16x8v ld8f_bf(const float* __restrict__ p) {
    const float4 v0 = *(const float4*)p;
    const float4 v1 = *(const float4*)(p + 4);
    bf16x8v r;
    r[0] = (short)f2bf(v0.x); r[1] = (short)f2bf(v0.y);
    r[2] = (short)f2bf(v0.z); r[3] = (short)f2bf(v0.w);
    r[4] = (short)f2bf(v1.x); r[5] = (short)f2bf(v1.y);
    r[6] = (short)f2bf(v1.z); r[7] = (short)f2bf(v1.w);
    return r;
}

struct AttnSmem {
    unsigned short lds_e[LL * ES];     // 18432 B
    unsigned short lds_eT[EE * ETS];   // 17664 B
    float s_lds[HH * 132];             //  4224 B
    unsigned short p_bf[HH * ETS];     //  2208 B
};
struct LnSmem { float red[8]; float stats[2]; };

// ===========================================================================
// Phase bodies (shared between mega cooperative kernel and fallback kernels)
// ===========================================================================

// ---- phase 0: pack. vb sections:
//   [0,256)      x cast (1024x512)
//   [256,1024)   W transposes (Wq,Wkv,Wf: 3 x 512x512, 256 tiles each)
//   [1024,1056)  WeT transpose (We 64x512 -> WeT 512x64)
//   [1056,1120)  M = per-head Wq_h @ We_h^T, stored as rows [1024,1536) of Wqkv_t
__device__ __forceinline__ void pack_body(int blk, int tid,
    const float* __restrict__ x, const float* __restrict__ Wq,
    const float* __restrict__ Wkv, const float* __restrict__ Wf,
    const float* __restrict__ We,
    unsigned short* __restrict__ xb, unsigned short* __restrict__ Wqkv_t,
    unsigned short* __restrict__ Wf_t, unsigned short* __restrict__ WeT_bf,
    float (*tile)[33])
{
    if (blk < 256) {                       // x cast: 512 float4 per block
        const int j = blk * 512 + tid * 2;
        #pragma unroll
        for (int i = 0; i < 2; ++i) {
            const float4 v = ((const float4*)x)[j + i];
            ushort4 u; u.x = f2bf(v.x); u.y = f2bf(v.y); u.z = f2bf(v.z); u.w = f2bf(v.w);
            ((ushort4*)xb)[j + i] = u;
        }
    } else if (blk < 1024) {               // 512x512 transpose-cast
        const int matId = (blk - 256) >> 8;
        const int t = (blk - 256) & 255;
        const float* src = matId == 0 ? Wq : (matId == 1 ? Wkv : Wf);
        unsigned short* dst = matId == 0 ? Wqkv_t : (matId == 1 ? Wqkv_t + DD * DD : Wf_t);
        const int xx = tid & 31, yy = tid >> 5;
        const int r0 = (t >> 4) * 32, c0 = (t & 15) * 32;
        #pragma unroll
        for (int j = 0; j < 32; j += 8)
            tile[yy + j][xx] = src[(r0 + yy + j) * DD + c0 + xx];
        __syncthreads();
        #pragma unroll
        for (int j = 0; j < 32; j += 8)
            dst[(c0 + yy + j) * DD + r0 + xx] = f2bf(tile[xx][yy + j]);
    } else if (blk < 1056) {               // WeT: We(64x512) -> (512x64)
        const int t = blk - 1024;          // 0..31
        const int xx = tid & 31, yy = tid >> 5;
        const int r0 = (t >> 4) * 32, c0 = (t & 15) * 32;   // r0 in {0,32}, c0 in [0,512)
        #pragma unroll
        for (int j = 0; j < 32; j += 8)
            tile[yy + j][xx] = We[(r0 + yy + j) * DD + c0 + xx];
        __syncthreads();
        #pragma unroll
        for (int j = 0; j < 32; j += 8)
            WeT_bf[(c0 + yy + j) * EE + r0 + xx] = f2bf(tile[xx][yy + j]);
    } else {
        // M[d, h*64+x] = sum_c Wq[d, h*64+c] * We[x, h*64+c]
        // stored transposed at Wqkv_t rows [1024 + h*64 + x], cols d.
        const int blk2 = blk - 1056;       // 0..63
        const int h = blk2 >> 3;
        const int d0 = (blk2 & 7) * 64;
        const int wave = tid >> 6, lane = tid & 63;
        const int quad = lane >> 4, l16 = lane & 15;
        const int dr = d0 + wave * 16;
        f32x4v acc[4];
        #pragma unroll
        for (int t = 0; t < 4; ++t) acc[t] = (f32x4v){0.f,0.f,0.f,0.f};
        #pragma unroll
        for (int ks = 0; ks < 2; ++ks) {
            const bf16x8v a = ld8f_bf(Wq + (dr + l16) * DD + h * CC + quad * 8 + ks * 32);
            #pragma unroll
            for (int t = 0; t < 4; ++t) {
                const bf16x8v bb = ld8f_bf(We + (t * 16 + l16) * DD + h * CC + quad * 8 + ks * 32);
                acc[t] = __builtin_amdgcn_mfma_f32_16x16x32_bf16(a, bb, acc[t], 0, 0, 0);
            }
        }
        #pragma unroll
        for (int t = 0; t < 4; ++t) {
            const int nrow = 1024 + h * CC + t * 16 + l16;
            #pragma unroll
            for (int r = 0; r < 4; ++r)
                Wqkv_t[nrow * DD + dr + quad * 4 + r] = f2bf(acc[t][r]);
        }
    }
}

// ---- phase 1: proj. [Q|KV|T](1024x1536) = xb @ [Wq|Wkv|M]. 384 vbs.
__device__ __forceinline__ void proj_body(int vb, int tid,
    const unsigned short* __restrict__ A, const unsigned short* __restrict__ Bm,
    unsigned short* __restrict__ Q_bf, unsigned short* __restrict__ KV_bf,
    unsigned short* __restrict__ KVT_bf, unsigned short* __restrict__ T_bf)
{
    const int wave = tid >> 6, lane = tid & 63;
    const int quad = lane >> 4, l16 = lane & 15;
    const int m0 = (vb / 24) * 64 + wave * 16;
    const int n0 = (vb % 24) * 64;
    const bf16x8v* Ap = (const bf16x8v*)(A + (m0 + l16) * DD) + quad;
    const bf16x8v* Bp = (const bf16x8v*)(Bm + (n0 + l16) * DD) + quad;
    f32x4v acc0 = {0.f,0.f,0.f,0.f}, acc1 = acc0, acc2 = acc0, acc3 = acc0;
    #pragma unroll 4
    for (int k = 0; k < 16; ++k) {
        const bf16x8v a = Ap[k * 4];
        acc0 = __builtin_amdgcn_mfma_f32_16x16x32_bf16(a, Bp[k * 4       ], acc0, 0, 0, 0);
        acc1 = __builtin_amdgcn_mfma_f32_16x16x32_bf16(a, Bp[k * 4 + 1024], acc1, 0, 0, 0);
        acc2 = __builtin_amdgcn_mfma_f32_16x16x32_bf16(a, Bp[k * 4 + 2048], acc2, 0, 0, 0);
        acc3 = __builtin_amdgcn_mfma_f32_16x16x32_bf16(a, Bp[k * 4 + 3072], acc3, 0, 0, 0);
    }
    const f32x4v accs[4] = {acc0, acc1, acc2, acc3};
    const int gm0 = m0 + quad * 4;
    #pragma unroll
    for (int t = 0; t < 4; ++t) {
        const int gn = n0 + t * 16 + l16;
        const int mat = gn >> 9, d = gn & 511, h = d >> 6, c = d & 63;
        ushort4 pk;
        pk.x = f2bf(accs[t][0]); pk.y = f2bf(accs[t][1]);
        pk.z = f2bf(accs[t][2]); pk.w = f2bf(accs[t][3]);
        unsigned short* dst = mat == 0 ? Q_bf : (mat == 1 ? KV_bf : T_bf);
        dst[(gm0 + 0) * DD + d] = pk.x;
        dst[(gm0 + 1) * DD + d] = pk.y;
        dst[(gm0 + 2) * DD + d] = pk.z;
        dst[(gm0 + 3) * DD + d] = pk.w;
        if (mat == 1) {
            const int b = gm0 >> 7, l0 = gm0 & 127;
            *(ushort4*)&KVT_bf[(((b * HH + h) * CC + c) << 7) + l0] = pk;
        }
    }
}

// ---- phase 2: qk. S1[b,h,q,k] = Q_h @ KV_h^T (fp32). 512 vbs.
__device__ __forceinline__ void qk_body(int vb, int tid,
    const unsigned short* __restrict__ Q_bf, const unsigned short* __restrict__ KV_bf,
    float* __restrict__ S1)
{
    const int wave = tid >> 6, lane = tid & 63;
    const int quad = lane >> 4, l16 = lane & 15;
    const int batch = vb >> 3;                  // b*8+h
    const int sub = vb & 7;
    const int b = batch >> 3, h = batch & 7;
    const int q0 = (sub >> 1) * 32 + (wave >> 1) * 16;
    const int k0 = (sub & 1) * 64 + (wave & 1) * 32;
    f32x4v acc[2];
    acc[0] = (f32x4v){0.f,0.f,0.f,0.f}; acc[1] = acc[0];
    const unsigned short* Ap = Q_bf + (b * LL + q0 + l16) * DD + h * CC + quad * 8;
    #pragma unroll
    for (int ks = 0; ks < 2; ++ks) {
        const bf16x8v a = *(const bf16x8v*)(Ap + ks * 32);
        #pragma unroll
        for (int t = 0; t < 2; ++t) {
            const bf16x8v bb = *(const bf16x8v*)(KV_bf + (b * LL + k0 + t * 16 + l16) * DD + h * CC + quad * 8 + ks * 32);
            acc[t] = __builtin_amdgcn_mfma_f32_16x16x32_bf16(a, bb, acc[t], 0, 0, 0);
        }
    }
    #pragma unroll
    for (int t = 0; t < 2; ++t)
        #pragma unroll
        for (int r = 0; r < 4; ++r)
            S1[((batch * LL + q0 + quad * 4 + r) << 7) + k0 + t * 16 + l16] = acc[t][r];
}

// ---- phase 3: attn. one vb per (b,q). 1024 vbs.
__device__ __forceinline__ void attn_body(int bq, int tid, AttnSmem* sm,
    const float* __restrict__ e, const int* __restrict__ adj,
    const float* __restrict__ S1, const unsigned short* __restrict__ T_bf,
    unsigned short* __restrict__ P1, unsigned short* __restrict__ G_bf)
{
    const int b = bq >> 7, q = bq & 127;
    const int wave = tid >> 6, lane = tid & 63, quad = lane >> 4, l16 = lane & 15;

    // ---- stage e tile (read once, coalesced float4) ----
    const float4* e4 = (const float4*)(e + (size_t)bq * (LL * EE));
    #pragma unroll
    for (int rep = 0; rep < 8; ++rep) {
        const int j = rep * 256 + tid;           // float4 index in tile
        const float4 v = e4[j];
        const int k = j >> 4, x0 = (j & 15) * 4;
        ushort4 u; u.x = f2bf(v.x); u.y = f2bf(v.y); u.z = f2bf(v.z); u.w = f2bf(v.w);
        *(ushort4*)&sm->lds_e[k * ES + x0] = u;
        sm->lds_eT[(x0    ) * ETS + k] = u.x;
        sm->lds_eT[(x0 + 1) * ETS + k] = u.y;
        sm->lds_eT[(x0 + 2) * ETS + k] = u.z;
        sm->lds_eT[(x0 + 3) * ETS + k] = u.w;
    }
    __syncthreads();

    // ---- scores: wave handles k-band [wave*32, wave*32+32) ----
    const int hh = l16 < 8 ? l16 : 7;
    const unsigned short* Trow = T_bf + bq * DD + hh * CC + quad * 8;
    const bf16x8v tb0 = *(const bf16x8v*)(Trow);
    const bf16x8v tb1 = *(const bf16x8v*)(Trow + 32);
    f32x4v sacc[2];
    #pragma unroll
    for (int mt = 0; mt < 2; ++mt) {
        sacc[mt] = (f32x4v){0.f,0.f,0.f,0.f};
        const int kb = wave * 32 + mt * 16;
        const bf16x8v a0 = *(const bf16x8v*)&sm->lds_e[(kb + l16) * ES + quad * 8];
        const bf16x8v a1 = *(const bf16x8v*)&sm->lds_e[(kb + l16) * ES + 32 + quad * 8];
        sacc[mt] = __builtin_amdgcn_mfma_f32_16x16x32_bf16(a0, tb0, sacc[mt], 0, 0, 0);
        sacc[mt] = __builtin_amdgcn_mfma_f32_16x16x32_bf16(a1, tb1, sacc[mt], 0, 0, 0);
    }
    if (l16 < 8) {
        #pragma unroll
        for (int mt = 0; mt < 2; ++mt) {
            const int kk0 = wave * 32 + mt * 16 + quad * 4;
            const float4 s1v = *(const float4*)&S1[(((b * HH + l16) * LL + q) << 7) + kk0];
            const int4 av = *(const int4*)&adj[bq * LL + kk0];
            float sv[4] = {s1v.x, s1v.y, s1v.z, s1v.w};
            const int am[4] = {av.x, av.y, av.z, av.w};
            float4 o;
            float* op = (float*)&o;
            #pragma unroll
            for (int r = 0; r < 4; ++r) {
                float sc = (sv[r] + sacc[mt][r]) * 0.125f;
                sc = (sc >= 0.f) ? sc : SLOPE * sc;
                op[r] = (am[r] == 0) ? -1e9f : sc;
            }
            *(float4*)&sm->s_lds[l16 * 132 + kk0] = o;
        }
    }
    __syncthreads();

    // ---- softmax per head: 32 threads/head, norm folded into P ----
    {
        const int h = tid >> 5, t5 = tid & 31;
        float m = -INFINITY;
        #pragma unroll
        for (int i = 0; i < 4; ++i) m = fmaxf(m, sm->s_lds[h * 132 + t5 + i * 32]);
        #pragma unroll
        for (int off = 16; off > 0; off >>= 1) m = fmaxf(m, __shfl_down(m, off, 32));
        m = __shfl(m, 0, 32);
        const int k0 = t5 * 4;
        float ev[4];
        #pragma unroll
        for (int i = 0; i < 4; ++i) ev[i] = __expf(sm->s_lds[h * 132 + k0 + i] - m);
        float l = ev[0] + ev[1] + ev[2] + ev[3];
        #pragma unroll
        for (int off = 16; off > 0; off >>= 1) l += __shfl_down(l, off, 32);
        l = __shfl(l, 0, 32);
        const float inv = 1.f / l;
        ushort4 pk;
        pk.x = f2bf(ev[0] * inv); pk.y = f2bf(ev[1] * inv);
        pk.z = f2bf(ev[2] * inv); pk.w = f2bf(ev[3] * inv);
        *(ushort4*)&sm->p_bf[h * ETS + k0] = pk;
        *(ushort4*)&P1[(((b * HH + h) * LL + q) << 7) + k0] = pk;
    }
    __syncthreads();

    // ---- G = P @ E^T : wave handles x-band [wave*16, wave*16+16) ----
    {
        const int hr = l16 < 8 ? l16 : 0;
        f32x4v g = {0.f,0.f,0.f,0.f};
        #pragma unroll
        for (int ks = 0; ks < 4; ++ks) {
            const bf16x8v a  = *(const bf16x8v*)&sm->p_bf[hr * ETS + ks * 32 + quad * 8];
            const bf16x8v bb = *(const bf16x8v*)&sm->lds_eT[(wave * 16 + l16) * ETS + ks * 32 + quad * 8];
            g = __builtin_amdgcn_mfma_f32_16x16x32_bf16(a, bb, g, 0, 0, 0);
        }
        if (quad < 2) {
            #pragma unroll
            for (int r = 0; r < 4; ++r)
                G_bf[bq * DD + (quad * 4 + r) * CC + wave * 16 + l16] = f2bf(g[r]);
        }
    }
}

// ---- phase 4: pv+o2 fused. 256 vbs.
__device__ __forceinline__ void pv_body(int vb, int tid,
    const unsigned short* __restrict__ P1, const unsigned short* __restrict__ KVT_bf,
    const unsigned short* __restrict__ G_bf, const unsigned short* __restrict__ WeT_bf,
    unsigned short* __restrict__ attn_bf)
{
    const int wave = tid >> 6, lane = tid & 63;
    const int quad = lane >> 4, l16 = lane & 15;
    const int batch = vb >> 2;           // b*8+h
    const int qt = vb & 3;
    const int q0 = qt * 32 + (wave >> 1) * 16;
    const int c0 = (wave & 1) * 32;
    const int b = batch >> 3, h = batch & 7;
    f32x4v acc[2];
    acc[0] = (f32x4v){0.f,0.f,0.f,0.f}; acc[1] = acc[0];

    const unsigned short* Ap = P1 + ((batch * LL + q0 + l16) << 7) + quad * 8;
    #pragma unroll
    for (int ks = 0; ks < 4; ++ks) {
        const bf16x8v a = *(const bf16x8v*)(Ap + ks * 32);
        #pragma unroll
        for (int t = 0; t < 2; ++t) {
            const bf16x8v bb = *(const bf16x8v*)(KVT_bf + ((batch * CC + c0 + t * 16 + l16) << 7) + quad * 8 + ks * 32);
            acc[t] = __builtin_amdgcn_mfma_f32_16x16x32_bf16(a, bb, acc[t], 0, 0, 0);
        }
    }
    const int gm = b * LL + q0;
    const unsigned short* Gp = G_bf + (gm + l16) * DD + h * CC + quad * 8;
    #pragma unroll
    for (int ks = 0; ks < 2; ++ks) {
        const bf16x8v a = *(const bf16x8v*)(Gp + ks * 32);
        #pragma unroll
        for (int t = 0; t < 2; ++t) {
            const bf16x8v bb = *(const bf16x8v*)(WeT_bf + (h * CC + c0 + t * 16 + l16) * EE + quad * 8 + ks * 32);
            acc[t] = __builtin_amdgcn_mfma_f32_16x16x32_bf16(a, bb, acc[t], 0, 0, 0);
        }
    }
    #pragma unroll
    for (int t = 0; t < 2; ++t) {
        const int d = h * CC + c0 + t * 16 + l16;
        #pragma unroll
        for (int r = 0; r < 4; ++r)
            attn_bf[(gm + quad * 4 + r) * DD + d] = f2bf(acc[t][r]);
    }
}

// ---- phase 5: ffn. vals = attn_bf @ Wf + bf. 256 vbs (32m x 64n tiles).
__device__ __forceinline__ void ffn_body(int vb, int tid,
    const unsigned short* __restrict__ A, const unsigned short* __restrict__ Bm,
    const float* __restrict__ bfv, float* __restrict__ vals)
{
    const int wave = tid >> 6, lane = tid & 63;
    const int quad = lane >> 4, l16 = lane & 15;
    const int m0 = (vb >> 3) * 32 + (wave >> 1) * 16;
    const int n0 = (vb & 7) * 64 + (wave & 1) * 32;
    const bf16x8v* Ap = (const bf16x8v*)(A + (m0 + l16) * DD) + quad;
    const bf16x8v* Bp = (const bf16x8v*)(Bm + (n0 + l16) * DD) + quad;
    f32x4v acc0 = {0.f,0.f,0.f,0.f}, acc1 = acc0;
    #pragma unroll 4
    for (int k = 0; k < 16; ++k) {
        const bf16x8v a = Ap[k * 4];
        acc0 = __builtin_amdgcn_mfma_f32_16x16x32_bf16(a, Bp[k * 4       ], acc0, 0, 0, 0);
        acc1 = __builtin_amdgcn_mfma_f32_16x16x32_bf16(a, Bp[k * 4 + 1024], acc1, 0, 0, 0);
    }
    const f32x4v accs[2] = {acc0, acc1};
    #pragma unroll
    for (int t = 0; t < 2; ++t) {
        const int gn = n0 + t * 16 + l16;
        const float bias = bfv[gn];
        #pragma unroll
        for (int r = 0; r < 4; ++r)
            vals[(m0 + quad * 4 + r) * DD + gn] = accs[t][r] + bias;
    }
}

// ---- phase 6: LayerNorm + ReLU. 1024 vbs (one row each).
__device__ __forceinline__ void ln_body(int row, int tid, LnSmem* sm,
    const float* __restrict__ vals, const float* __restrict__ gamma,
    const float* __restrict__ beta, float* __restrict__ out)
{
    const float v0 = vals[row * DD + tid];
    const float v1 = vals[row * DD + tid + 256];
    float ls = v0 + v1;
    float lss = v0 * v0 + v1 * v1;
    #pragma unroll
    for (int off = 32; off > 0; off >>= 1) {
        ls += __shfl_down(ls, off);
        lss += __shfl_down(lss, off);
    }
    const int wid = tid >> 6;
    if ((tid & 63) == 0) { sm->red[wid * 2] = ls; sm->red[wid * 2 + 1] = lss; }
    __syncthreads();
    if (tid == 0) {
        float ts = 0.f, tss = 0.f;
        for (int w = 0; w < 4; ++w) { ts += sm->red[w * 2]; tss += sm->red[w * 2 + 1]; }
        const float mu = ts / (float)DD;
        const float var = tss / (float)DD - mu * mu;
        sm->stats[0] = mu;
        sm->stats[1] = rsqrtf(var + EPS);
    }
    __syncthreads();
    const float mu = sm->stats[0], rsig = sm->stats[1];
    const float o0 = (v0 - mu) * rsig * gamma[tid] + beta[tid];
    const float o1 = (v1 - mu) * rsig * gamma[tid + 256] + beta[tid + 256];
    out[row * DD + tid] = fmaxf(o0, 0.f);
    out[row * DD + tid + 256] = fmaxf(o1, 0.f);
}

// ===========================================================================
// Mega cooperative kernel: all 7 phases, grid-stride, grid.sync between.
// ===========================================================================
struct MegaArgs {
    const float *x; const int *adj; const float *e;
    const float *Wq, *Wkv, *We, *Wf, *bfv, *gam, *bet;
    float *out;
    unsigned short *xb, *Wqkv_t, *Wf_t, *WeT_bf;
    unsigned short *Q_bf, *KV_bf, *KVT_bf, *T_bf, *P1, *G_bf, *attn_bf;
    float *S1, *vals;
};

__global__ __launch_bounds__(256) void mega(MegaArgs A)
{
    __shared__ union SmU {
        AttnSmem at;
        float tile[32][33];
        LnSmem ln;
    } sm;
    cg::grid_group grid = cg::this_grid();
    const int tid = threadIdx.x;
    const int NB = gridDim.x;

    for (int vb = blockIdx.x; vb < NPACK; vb += NB) {
        __syncthreads();
        pack_body(vb, tid, A.x, A.Wq, A.Wkv, A.Wf, A.We,
                  A.xb, A.Wqkv_t, A.Wf_t, A.WeT_bf, sm.tile);
    }
    __threadfence(); grid.sync();

    for (int vb = blockIdx.x; vb < 384; vb += NB)
        proj_body(vb, tid, A.xb, A.Wqkv_t, A.Q_bf, A.KV_bf, A.KVT_bf, A.T_bf);
    __threadfence(); grid.sync();

    for (int vb = blockIdx.x; vb < 512; vb += NB)
        qk_body(vb, tid, A.Q_bf, A.KV_bf, A.S1);
    __threadfence(); grid.sync();

    for (int vb = blockIdx.x; vb < 1024; vb += NB) {
        attn_body(vb, tid, &sm.at, A.e, A.adj, A.S1, A.T_bf, A.P1, A.G_bf);
        __syncthreads();
    }
    __threadfence(); grid.sync();

    for (int vb = blockIdx.x; vb < 256; vb += NB)
        pv_body(vb, tid, A.P1, A.KVT_bf, A.G_bf, A.WeT_bf, A.attn_bf);
    __threadfence(); grid.sync();

    for (int vb = blockIdx.x; vb < 256; vb += NB)
        ffn_body(vb, tid, A.attn_bf, A.Wf_t, A.bfv, A.vals);
    __threadfence(); grid.sync();

    for (int vb = blockIdx.x; vb < 1024; vb += NB)
        ln_body(vb, tid, &sm.ln, A.vals, A.gam, A.bet, A.out);
}

// ===========================================================================
// Fallback separate kernels (used only if cooperative launch is unavailable)
// ===========================================================================
__global__ __launch_bounds__(256) void pack_k(
    const float* x, const float* Wq, const float* Wkv, const float* Wf, const float* We,
    unsigned short* xb, unsigned short* Wqkv_t, unsigned short* Wf_t, unsigned short* WeT_bf)
{
    __shared__ float tile[32][33];
    pack_body(blockIdx.x, threadIdx.x, x, Wq, Wkv, Wf, We, xb, Wqkv_t, Wf_t, WeT_bf, tile);
}
__global__ __launch_bounds__(256) void proj_k(
    const unsigned short* A, const unsigned short* Bm, unsigned short* Q_bf,
    unsigned short* KV_bf, unsigned short* KVT_bf, unsigned short* T_bf)
{
    proj_body(blockIdx.x, threadIdx.x, A, Bm, Q_bf, KV_bf, KVT_bf, T_bf);
}
__global__ __launch_bounds__(256) void qk_k(
    const unsigned short* Q_bf, const unsigned short* KV_bf, float* S1)
{
    qk_body(blockIdx.x, threadIdx.x, Q_bf, KV_bf, S1);
}
__global__ __launch_bounds__(256) void attn_k(
    const float* e, const int* adj, const float* S1, const unsigned short* T_bf,
    unsigned short* P1, unsigned short* G_bf)
{
    __shared__ AttnSmem s;
    attn_body(blockIdx.x, threadIdx.x, &s, e, adj, S1, T_bf, P1, G_bf);
}
__global__ __launch_bounds__(256) void pv_k(
    const unsigned short* P1, const unsigned short* KVT_bf, const unsigned short* G_bf,
    const unsigned short* WeT_bf, unsigned short* attn_bf)
{
    pv_body(blockIdx.x, threadIdx.x, P1, KVT_bf, G_bf, WeT_bf, attn_bf);
}
__global__ __launch_bounds__(256) void ffn_k(
    const unsigned short* A, const unsigned short* Bm, const float* bfv, float* vals)
{
    ffn_body(blockIdx.x, threadIdx.x, A, Bm, bfv, vals);
}
__global__ __launch_bounds__(256) void ln_k(
    const float* vals, const float* gamma, const float* beta, float* out)
{
    __shared__ LnSmem s;
    ln_body(blockIdx.x, threadIdx.x, &s, vals, gamma, beta, out);
}

// ---------------------------------------------------------------------------
extern "C" void kernel_launch(void* const* d_in, const int* in_sizes, int n_in,
                              void* d_out, int out_size, void* d_ws, size_t ws_size,
                              hipStream_t stream)
{
    const float* x    = (const float*)d_in[0];
    const int*   adj  = (const int*)  d_in[1];
    const float* e    = (const float*)d_in[2];
    const float* Wq   = (const float*)d_in[3];
    const float* Wkv  = (const float*)d_in[4];
    const float* We   = (const float*)d_in[5];
    const float* Wf   = (const float*)d_in[6];
    const float* bf   = (const float*)d_in[7];
    const float* gam  = (const float*)d_in[8];
    const float* bet  = (const float*)d_in[9];
    float* out = (float*)d_out;

    char* w = (char*)d_ws;
    unsigned short* Q_bf    = (unsigned short*)(w);                 // 1 MB
    unsigned short* KV_bf   = (unsigned short*)(w + (1u  << 20));   // 1 MB
    unsigned short* KVT_bf  = (unsigned short*)(w + (2u  << 20));   // 1 MB
    float*          S1      = (float*)         (w + (3u  << 20));   // 4 MB
    unsigned short* T_bf    = (unsigned short*)(w + (7u  << 20));   // 1 MB
    unsigned short* P1      = (unsigned short*)(w + (8u  << 20));   // 2 MB
    unsigned short* G_bf    = (unsigned short*)(w + (10u << 20));   // 1 MB
    unsigned short* attn_bf = (unsigned short*)(w + (11u << 20));   // 1 MB (no alias!)
    float*          vals    = (float*)         (w + (12u << 20));   // 2 MB
    unsigned short* xb      = (unsigned short*)(w + (14u << 20));   // 1 MB
    unsigned short* Wqkv_t  = (unsigned short*)(w + (15u << 20));   // 1.5 MB (rows: Q|KV|M)
    unsigned short* Wf_t    = (unsigned short*)(w + (16u << 20) + (512u << 10)); // 0.5 MB
    unsigned short* WeT_bf  = (unsigned short*)(w + (17u << 20));   // 64 KB

    MegaArgs ma;
    ma.x = x; ma.adj = adj; ma.e = e;
    ma.Wq = Wq; ma.Wkv = Wkv; ma.We = We; ma.Wf = Wf;
    ma.bfv = bf; ma.gam = gam; ma.bet = bet;
    ma.out = out;
    ma.xb = xb; ma.Wqkv_t = Wqkv_t; ma.Wf_t = Wf_t; ma.WeT_bf = WeT_bf;
    ma.Q_bf = Q_bf; ma.KV_bf = KV_bf; ma.KVT_bf = KVT_bf; ma.T_bf = T_bf;
    ma.P1 = P1; ma.G_bf = G_bf; ma.attn_bf = attn_bf;
    ma.S1 = S1; ma.vals = vals;

    static int s_grid = 0;
    if (s_grid == 0) {
        int nb = 0;
        hipError_t qe = hipOccupancyMaxActiveBlocksPerMultiprocessor(&nb, mega, 256, 0);
        if (qe != hipSuccess || nb < 1) {
            s_grid = -1;                         // cooperative path unusable
        } else {
            long g = (long)nb * 256;
            if (g > 1024) g = 1024;
            s_grid = (int)g;
        }
    }

    bool done = false;
    if (s_grid > 0) {
        void* kargs[] = { (void*)&ma };
        hipError_t err = hipLaunchCooperativeKernel(mega, dim3(s_grid), dim3(256),
                                                    kargs, 0u, stream);
        done = (err == hipSuccess);
    }
    if (!done) {
        pack_k<<<NPACK, 256, 0, stream>>>(x, Wq, Wkv, Wf, We, xb, Wqkv_t, Wf_t, WeT_bf);
        proj_k<<<384, 256, 0, stream>>>(xb, Wqkv_t, Q_bf, KV_bf, KVT_bf, T_bf);
        qk_k<<<512, 256, 0, stream>>>(Q_bf, KV_bf, S1);
        attn_k<<<1024, 256, 0, stream>>>(e, adj, S1, T_bf, P1, G_bf);
        pv_k<<<256, 256, 0, stream>>>(P1, KVT_bf, G_bf, WeT_bf, attn_bf);
        ffn_k<<<256, 256, 0, stream>>>(attn_bf, Wf_t, bf, vals);
        ln_k<<<1024, 256, 0, stream>>>(vals, gam, bet, out);
    }
}

// Round 4
// 140.635 us; speedup vs baseline: 3.6640x; 3.6640x over previous
//
#include <hip/hip_runtime.h>
#include <hip/hip_bf16.h>
#include <math.h>

// Problem constants
#define BB 8
#define LL 128
#define DD 512
#define EE 64
#define HH 8
#define CC 64        // D/H
#define SLOPE 0.2f
#define EPS 1e-5f

typedef short bf16x8v __attribute__((ext_vector_type(8)));
typedef float f32x4v __attribute__((ext_vector_type(4)));

static __device__ __forceinline__ unsigned short f2bf(float f) {
    union { float f; unsigned u; } v; v.f = f;
    unsigned r = v.u + 0x7FFFu + ((v.u >> 16) & 1u);   // RNE
    return (unsigned short)(r >> 16);
}

static __device__ __forceinline__ bf16x8v ld8f_bf(const float* __restrict__ p) {
    const float4 v0 = *(const float4*)p;
    const float4 v1 = *(const float4*)(p + 4);
    bf16x8v r;
    r[0] = (short)f2bf(v0.x); r[1] = (short)f2bf(v0.y);
    r[2] = (short)f2bf(v0.z); r[3] = (short)f2bf(v0.w);
    r[4] = (short)f2bf(v1.x); r[5] = (short)f2bf(v1.y);
    r[6] = (short)f2bf(v1.z); r[7] = (short)f2bf(v1.w);
    return r;
}

// ---------------------------------------------------------------------------
// pack_all: x->bf16; Wq/Wkv/Wf transpose-cast; We cast; WeT transpose;
//           M = per-head Wq_h @ We_h^T appended as rows [1024,1536) of Wqkv_t
//           (so proj can emit T = x@M directly).
// ---------------------------------------------------------------------------
__global__ __launch_bounds__(256) void pack_all(
    const float* __restrict__ x, const float* __restrict__ Wq,
    const float* __restrict__ Wkv, const float* __restrict__ Wf,
    const float* __restrict__ We,
    unsigned short* __restrict__ xb, unsigned short* __restrict__ Wqkv_t,
    unsigned short* __restrict__ Wf_t, unsigned short* __restrict__ We_bf,
    unsigned short* __restrict__ WeT_bf)
{
    const int blk = blockIdx.x, tid = threadIdx.x;
    if (blk < 256) {                       // x cast: 512 float4 per block
        const int j = blk * 512 + tid * 2;
        #pragma unroll
        for (int i = 0; i < 2; ++i) {
            const float4 v = ((const float4*)x)[j + i];
            ushort4 u; u.x = f2bf(v.x); u.y = f2bf(v.y); u.z = f2bf(v.z); u.w = f2bf(v.w);
            ((ushort4*)xb)[j + i] = u;
        }
    } else if (blk < 1024) {               // 512x512 transpose-cast
        __shared__ float tile[32][33];
        const int matId = (blk - 256) >> 8;
        const int t = (blk - 256) & 255;
        const float* src = matId == 0 ? Wq : (matId == 1 ? Wkv : Wf);
        unsigned short* dst = matId == 0 ? Wqkv_t : (matId == 1 ? Wqkv_t + DD * DD : Wf_t);
        const int xx = tid & 31, yy = tid >> 5;
        const int r0 = (t >> 4) * 32, c0 = (t & 15) * 32;
        #pragma unroll
        for (int j = 0; j < 32; j += 8)
            tile[yy + j][xx] = src[(r0 + yy + j) * DD + c0 + xx];
        __syncthreads();
        #pragma unroll
        for (int j = 0; j < 32; j += 8)
            dst[(c0 + yy + j) * DD + r0 + xx] = f2bf(tile[xx][yy + j]);
    } else if (blk < 1040) {               // We cast: 64x512 = 8192 float4
        const int j = (blk - 1024) * 512 + tid * 2;
        #pragma unroll
        for (int i = 0; i < 2; ++i) {
            const float4 v = ((const float4*)We)[j + i];
            ushort4 u; u.x = f2bf(v.x); u.y = f2bf(v.y); u.z = f2bf(v.z); u.w = f2bf(v.w);
            ((ushort4*)We_bf)[j + i] = u;
        }
    } else if (blk < 1072) {               // WeT: We(64x512) -> (512x64)
        __shared__ float tile[32][33];
        const int t = blk - 1040;
        const int xx = tid & 31, yy = tid >> 5;
        const int r0 = (t >> 4) * 32, c0 = (t & 15) * 32;   // r0 in [0,64), c0 in [0,512)
        #pragma unroll
        for (int j = 0; j < 32; j += 8)
            tile[yy + j][xx] = We[(r0 + yy + j) * DD + c0 + xx];
        __syncthreads();
        #pragma unroll
        for (int j = 0; j < 32; j += 8)
            WeT_bf[(c0 + yy + j) * EE + r0 + xx] = f2bf(tile[xx][yy + j]);
    } else {
        // M[d, h*64+x] = sum_c Wq[d, h*64+c] * We[x, h*64+c]
        // stored transposed at Wqkv_t rows [1024 + h*64 + x], cols d.
        const int blk2 = blk - 1072;       // 0..63
        const int h = blk2 >> 3;
        const int d0 = (blk2 & 7) * 64;
        const int wave = tid >> 6, lane = tid & 63;
        const int quad = lane >> 4, l16 = lane & 15;
        const int dr = d0 + wave * 16;     // this wave's 16 d-rows
        f32x4v acc[4];
        #pragma unroll
        for (int t = 0; t < 4; ++t) acc[t] = (f32x4v){0.f,0.f,0.f,0.f};
        #pragma unroll
        for (int ks = 0; ks < 2; ++ks) {
            const bf16x8v a = ld8f_bf(Wq + (dr + l16) * DD + h * CC + quad * 8 + ks * 32);
            #pragma unroll
            for (int t = 0; t < 4; ++t) {
                const bf16x8v bb = ld8f_bf(We + (t * 16 + l16) * DD + h * CC + quad * 8 + ks * 32);
                acc[t] = __builtin_amdgcn_mfma_f32_16x16x32_bf16(a, bb, acc[t], 0, 0, 0);
            }
        }
        #pragma unroll
        for (int t = 0; t < 4; ++t) {
            const int nrow = 1024 + h * CC + t * 16 + l16;
            #pragma unroll
            for (int r = 0; r < 4; ++r)
                Wqkv_t[nrow * DD + dr + quad * 4 + r] = f2bf(acc[t][r]);
        }
    }
}

// ---------------------------------------------------------------------------
// proj_gemm: [Q|KV|T](1024x1536) = xb(1024x512) @ [Wq|Wkv|M]; epilogue writes
// Q_bf, KV_bf, T_bf as (bq,d) bf16 and KVT_bf as (b,h,c,k=l) bf16.
// grid dim3(24,16) = 384 blocks.
// ---------------------------------------------------------------------------
__global__ __launch_bounds__(256) void proj_gemm(
    const unsigned short* __restrict__ A, const unsigned short* __restrict__ Bm,
    unsigned short* __restrict__ Q_bf, unsigned short* __restrict__ KV_bf,
    unsigned short* __restrict__ KVT_bf, unsigned short* __restrict__ T_bf)
{
    const int wave = threadIdx.x >> 6, lane = threadIdx.x & 63;
    const int quad = lane >> 4, l16 = lane & 15;
    const int m0 = blockIdx.y * 64 + wave * 16;
    const int n0 = blockIdx.x * 64;
    const bf16x8v* Ap = (const bf16x8v*)(A + (m0 + l16) * DD) + quad;
    const bf16x8v* Bp = (const bf16x8v*)(Bm + (n0 + l16) * DD) + quad;
    f32x4v acc0 = {0.f,0.f,0.f,0.f}, acc1 = acc0, acc2 = acc0, acc3 = acc0;
    #pragma unroll 4
    for (int k = 0; k < 16; ++k) {
        const bf16x8v a = Ap[k * 4];
        acc0 = __builtin_amdgcn_mfma_f32_16x16x32_bf16(a, Bp[k * 4       ], acc0, 0, 0, 0);
        acc1 = __builtin_amdgcn_mfma_f32_16x16x32_bf16(a, Bp[k * 4 + 1024], acc1, 0, 0, 0);
        acc2 = __builtin_amdgcn_mfma_f32_16x16x32_bf16(a, Bp[k * 4 + 2048], acc2, 0, 0, 0);
        acc3 = __builtin_amdgcn_mfma_f32_16x16x32_bf16(a, Bp[k * 4 + 3072], acc3, 0, 0, 0);
    }
    const f32x4v accs[4] = {acc0, acc1, acc2, acc3};
    const int gm0 = m0 + quad * 4;
    #pragma unroll
    for (int t = 0; t < 4; ++t) {
        const int gn = n0 + t * 16 + l16;
        const int mat = gn >> 9, d = gn & 511, h = d >> 6, c = d & 63;
        ushort4 pk;
        pk.x = f2bf(accs[t][0]); pk.y = f2bf(accs[t][1]);
        pk.z = f2bf(accs[t][2]); pk.w = f2bf(accs[t][3]);
        unsigned short* dst = mat == 0 ? Q_bf : (mat == 1 ? KV_bf : T_bf);
        dst[(gm0 + 0) * DD + d] = pk.x;
        dst[(gm0 + 1) * DD + d] = pk.y;
        dst[(gm0 + 2) * DD + d] = pk.z;
        dst[(gm0 + 3) * DD + d] = pk.w;
        if (mat == 1) {
            const int b = gm0 >> 7, l0 = gm0 & 127;
            *(ushort4*)&KVT_bf[(((b * HH + h) * CC + c) << 7) + l0] = pk;
        }
    }
}

// ---------------------------------------------------------------------------
// qk_s1: S1[b,h,q,k] = Q_h @ KV_h^T (fp32).  512 blocks (2/CU):
// block = (batch 64) x (q-tile of 32) x (k-tile of 64); 4 waves:
// wave covers q-half 16 x k-half 32 (2 acc tiles), K=64.
// ---------------------------------------------------------------------------
__global__ __launch_bounds__(256) void qk_s1(
    const unsigned short* __restrict__ Q_bf, const unsigned short* __restrict__ KV_bf,
    float* __restrict__ S1)
{
    const int wave = threadIdx.x >> 6, lane = threadIdx.x & 63;
    const int quad = lane >> 4, l16 = lane & 15;
    const int bid = blockIdx.x;
    const int batch = bid >> 3;                  // b*8+h
    const int sub = bid & 7;
    const int b = batch >> 3, h = batch & 7;
    const int q0 = (sub >> 1) * 32 + (wave >> 1) * 16;
    const int k0 = (sub & 1) * 64 + (wave & 1) * 32;
    f32x4v acc[2];
    acc[0] = (f32x4v){0.f,0.f,0.f,0.f}; acc[1] = acc[0];
    const unsigned short* Ap = Q_bf + (b * LL + q0 + l16) * DD + h * CC + quad * 8;
    #pragma unroll
    for (int ks = 0; ks < 2; ++ks) {
        const bf16x8v a = *(const bf16x8v*)(Ap + ks * 32);
        #pragma unroll
        for (int t = 0; t < 2; ++t) {
            const bf16x8v bb = *(const bf16x8v*)(KV_bf + (b * LL + k0 + t * 16 + l16) * DD + h * CC + quad * 8 + ks * 32);
            acc[t] = __builtin_amdgcn_mfma_f32_16x16x32_bf16(a, bb, acc[t], 0, 0, 0);
        }
    }
    #pragma unroll
    for (int t = 0; t < 2; ++t)
        #pragma unroll
        for (int r = 0; r < 4; ++r)
            S1[((batch * LL + q0 + quad * 4 + r) << 7) + k0 + t * 16 + l16] = acc[t][r];
}

// ---------------------------------------------------------------------------
// attn_fused: one block per (b,q).
//  - stage e tile to LDS in (k,x) and (x,k) bf16 layouts
//  - S2 = E @ T^T via MFMA (N=8 padded to 16); s = leaky((S1+S2)/8) masked
//  - softmax over k per head (wave-shuffle, norm folded into P)
//  - write P1 (b,h,q,k) bf16; G = P @ E^T via MFMA -> G_bf (bq, h*64+x)
// ---------------------------------------------------------------------------
#define ES 72      // lds_e row stride (ushort):   144B -> bank rot 4
#define ETS 138    // lds_eT/p_bf row stride: 276B -> write Δ=276dw mod32=20 -> 8 banks (2-way)
__global__ __launch_bounds__(256) void attn_fused(
    const float* __restrict__ e, const int* __restrict__ adj,
    const float* __restrict__ S1, const unsigned short* __restrict__ T_bf,
    unsigned short* __restrict__ P1, unsigned short* __restrict__ G_bf)
{
    __shared__ unsigned short lds_e[LL * ES];     // 18432 B
    __shared__ unsigned short lds_eT[EE * ETS];   // 17664 B
    __shared__ float s_lds[HH * 132];             //  4224 B
    __shared__ unsigned short p_bf[HH * ETS];     //  2208 B

    const int bq = blockIdx.x;
    const int b = bq >> 7, q = bq & 127;
    const int tid = threadIdx.x;
    const int wave = tid >> 6, lane = tid & 63, quad = lane >> 4, l16 = lane & 15;

    // ---- stage e tile (read once, coalesced float4) ----
    const float4* e4 = (const float4*)(e + (size_t)bq * (LL * EE));
    #pragma unroll
    for (int rep = 0; rep < 8; ++rep) {
        const int j = rep * 256 + tid;           // float4 index in tile
        const float4 v = e4[j];
        const int k = j >> 4, x0 = (j & 15) * 4;
        ushort4 u; u.x = f2bf(v.x); u.y = f2bf(v.y); u.z = f2bf(v.z); u.w = f2bf(v.w);
        *(ushort4*)&lds_e[k * ES + x0] = u;
        lds_eT[(x0    ) * ETS + k] = u.x;
        lds_eT[(x0 + 1) * ETS + k] = u.y;
        lds_eT[(x0 + 2) * ETS + k] = u.z;
        lds_eT[(x0 + 3) * ETS + k] = u.w;
    }
    __syncthreads();

    // ---- scores: wave handles k-band [wave*32, wave*32+32) ----
    const int hh = l16 < 8 ? l16 : 7;
    const unsigned short* Trow = T_bf + bq * DD + hh * CC + quad * 8;
    const bf16x8v tb0 = *(const bf16x8v*)(Trow);
    const bf16x8v tb1 = *(const bf16x8v*)(Trow + 32);
    f32x4v sacc[2];
    #pragma unroll
    for (int mt = 0; mt < 2; ++mt) {
        sacc[mt] = (f32x4v){0.f,0.f,0.f,0.f};
        const int kb = wave * 32 + mt * 16;
        const bf16x8v a0 = *(const bf16x8v*)&lds_e[(kb + l16) * ES + quad * 8];
        const bf16x8v a1 = *(const bf16x8v*)&lds_e[(kb + l16) * ES + 32 + quad * 8];
        sacc[mt] = __builtin_amdgcn_mfma_f32_16x16x32_bf16(a0, tb0, sacc[mt], 0, 0, 0);
        sacc[mt] = __builtin_amdgcn_mfma_f32_16x16x32_bf16(a1, tb1, sacc[mt], 0, 0, 0);
    }
    if (l16 < 8) {
        #pragma unroll
        for (int mt = 0; mt < 2; ++mt) {
            const int kk0 = wave * 32 + mt * 16 + quad * 4;
            const float4 s1v = *(const float4*)&S1[(((b * HH + l16) * LL + q) << 7) + kk0];
            const int4 av = *(const int4*)&adj[bq * LL + kk0];
            float sv[4] = {s1v.x, s1v.y, s1v.z, s1v.w};
            const int am[4] = {av.x, av.y, av.z, av.w};
            float4 o;
            float* op = (float*)&o;
            #pragma unroll
            for (int r = 0; r < 4; ++r) {
                float sc = (sv[r] + sacc[mt][r]) * 0.125f;
                sc = (sc >= 0.f) ? sc : SLOPE * sc;
                op[r] = (am[r] == 0) ? -1e9f : sc;
            }
            *(float4*)&s_lds[l16 * 132 + kk0] = o;
        }
    }
    __syncthreads();

    // ---- softmax per head: 32 threads/head, norm folded into P ----
    {
        const int h = tid >> 5, t5 = tid & 31;
        float m = -INFINITY;
        #pragma unroll
        for (int i = 0; i < 4; ++i) m = fmaxf(m, s_lds[h * 132 + t5 + i * 32]);
        #pragma unroll
        for (int off = 16; off > 0; off >>= 1) m = fmaxf(m, __shfl_down(m, off, 32));
        m = __shfl(m, 0, 32);
        const int k0 = t5 * 4;
        float ev[4];
        #pragma unroll
        for (int i = 0; i < 4; ++i) ev[i] = __expf(s_lds[h * 132 + k0 + i] - m);
        float l = ev[0] + ev[1] + ev[2] + ev[3];
        #pragma unroll
        for (int off = 16; off > 0; off >>= 1) l += __shfl_down(l, off, 32);
        l = __shfl(l, 0, 32);
        const float inv = 1.f / l;
        ushort4 pk;
        pk.x = f2bf(ev[0] * inv); pk.y = f2bf(ev[1] * inv);
        pk.z = f2bf(ev[2] * inv); pk.w = f2bf(ev[3] * inv);
        *(ushort4*)&p_bf[h * ETS + k0] = pk;
        *(ushort4*)&P1[(((b * HH + h) * LL + q) << 7) + k0] = pk;
    }
    __syncthreads();

    // ---- G = P @ E^T : wave handles x-band [wave*16, wave*16+16) ----
    {
        const int hr = l16 < 8 ? l16 : 0;
        f32x4v g = {0.f,0.f,0.f,0.f};
        #pragma unroll
        for (int ks = 0; ks < 4; ++ks) {
            const bf16x8v a  = *(const bf16x8v*)&p_bf[hr * ETS + ks * 32 + quad * 8];
            const bf16x8v bb = *(const bf16x8v*)&lds_eT[(wave * 16 + l16) * ETS + ks * 32 + quad * 8];
            g = __builtin_amdgcn_mfma_f32_16x16x32_bf16(a, bb, g, 0, 0, 0);
        }
        if (quad < 2) {
            #pragma unroll
            for (int r = 0; r < 4; ++r)
                G_bf[bq * DD + (quad * 4 + r) * CC + wave * 16 + l16] = f2bf(g[r]);
        }
    }
}

// ---------------------------------------------------------------------------
// pv_o2_gemm (FUSED pv + o2), 256 blocks (1/CU):
//   block = (batch b*8+h) x (q-tile 32); 4 waves: wave = q-half 16 x c-half 32.
//   acc  = P1_h @ KV_h        (K=128)
//   acc += G_h  @ We_h (WeT)  (K=64)
//   attn_bf[bq,d] = bf16(acc)
// ---------------------------------------------------------------------------
__global__ __launch_bounds__(256) void pv_o2_gemm(
    const unsigned short* __restrict__ P1, const unsigned short* __restrict__ KVT_bf,
    const unsigned short* __restrict__ G_bf, const unsigned short* __restrict__ WeT_bf,
    unsigned short* __restrict__ attn_bf)
{
    const int wave = threadIdx.x >> 6, lane = threadIdx.x & 63;
    const int quad = lane >> 4, l16 = lane & 15;
    const int batch = blockIdx.x >> 2;           // b*8+h
    const int qt = blockIdx.x & 3;
    const int q0 = qt * 32 + (wave >> 1) * 16;
    const int c0 = (wave & 1) * 32;
    const int b = batch >> 3, h = batch & 7;
    f32x4v acc[2];
    acc[0] = (f32x4v){0.f,0.f,0.f,0.f}; acc[1] = acc[0];

    // --- stage 1: P @ V (K = 128 keys) ---
    const unsigned short* Ap = P1 + ((batch * LL + q0 + l16) << 7) + quad * 8;
    #pragma unroll
    for (int ks = 0; ks < 4; ++ks) {
        const bf16x8v a = *(const bf16x8v*)(Ap + ks * 32);
        #pragma unroll
        for (int t = 0; t < 2; ++t) {
            const bf16x8v bb = *(const bf16x8v*)(KVT_bf + ((batch * CC + c0 + t * 16 + l16) << 7) + quad * 8 + ks * 32);
            acc[t] = __builtin_amdgcn_mfma_f32_16x16x32_bf16(a, bb, acc[t], 0, 0, 0);
        }
    }

    // --- stage 2: G @ We (K = 64 edge dims), same output tile ---
    const int gm = b * LL + q0;
    const unsigned short* Gp = G_bf + (gm + l16) * DD + h * CC + quad * 8;
    #pragma unroll
    for (int ks = 0; ks < 2; ++ks) {
        const bf16x8v a = *(const bf16x8v*)(Gp + ks * 32);
        #pragma unroll
        for (int t = 0; t < 2; ++t) {
            const bf16x8v bb = *(const bf16x8v*)(WeT_bf + (h * CC + c0 + t * 16 + l16) * EE + quad * 8 + ks * 32);
            acc[t] = __builtin_amdgcn_mfma_f32_16x16x32_bf16(a, bb, acc[t], 0, 0, 0);
        }
    }

    // --- epilogue: bf16 attn output ---
    #pragma unroll
    for (int t = 0; t < 2; ++t) {
        const int d = h * CC + c0 + t * 16 + l16;
        #pragma unroll
        for (int r = 0; r < 4; ++r)
            attn_bf[(gm + quad * 4 + r) * DD + d] = f2bf(acc[t][r]);
    }
}

// ---------------------------------------------------------------------------
// ffn_gemm: vals = attn_bf @ Wf + bf (fp32). M=1024 N=512 K=512.
// grid dim3(8,32) = 256 blocks (1/CU); block = 32m x 64n, 4 waves:
// wave = m-half 16 x n-half 32 (2 acc tiles).
// ---------------------------------------------------------------------------
__global__ __launch_bounds__(256) void ffn_gemm(
    const unsigned short* __restrict__ A, const unsigned short* __restrict__ Bm,
    const float* __restrict__ bfv, float* __restrict__ vals)
{
    const int wave = threadIdx.x >> 6, lane = threadIdx.x & 63;
    const int quad = lane >> 4, l16 = lane & 15;
    const int m0 = blockIdx.y * 32 + (wave >> 1) * 16;
    const int n0 = blockIdx.x * 64 + (wave & 1) * 32;
    const bf16x8v* Ap = (const bf16x8v*)(A + (m0 + l16) * DD) + quad;
    const bf16x8v* Bp = (const bf16x8v*)(Bm + (n0 + l16) * DD) + quad;
    f32x4v acc0 = {0.f,0.f,0.f,0.f}, acc1 = acc0;
    #pragma unroll 4
    for (int k = 0; k < 16; ++k) {
        const bf16x8v a = Ap[k * 4];
        acc0 = __builtin_amdgcn_mfma_f32_16x16x32_bf16(a, Bp[k * 4       ], acc0, 0, 0, 0);
        acc1 = __builtin_amdgcn_mfma_f32_16x16x32_bf16(a, Bp[k * 4 + 1024], acc1, 0, 0, 0);
    }
    const f32x4v accs[2] = {acc0, acc1};
    #pragma unroll
    for (int t = 0; t < 2; ++t) {
        const int gn = n0 + t * 16 + l16;
        const float bias = bfv[gn];
        #pragma unroll
        for (int r = 0; r < 4; ++r)
            vals[(m0 + quad * 4 + r) * DD + gn] = accs[t][r] + bias;
    }
}

// ---------------------------------------------------------------------------
// LayerNorm + ReLU (1024 blocks)
// ---------------------------------------------------------------------------
__global__ __launch_bounds__(256) void ln_kernel(
    const float* __restrict__ vals, const float* __restrict__ gamma,
    const float* __restrict__ beta, float* __restrict__ out)
{
    __shared__ float red[8];
    __shared__ float stats[2];
    const int row = blockIdx.x;
    const int tid = threadIdx.x;
    const float v0 = vals[row * DD + tid];
    const float v1 = vals[row * DD + tid + 256];
    float ls = v0 + v1;
    float lss = v0 * v0 + v1 * v1;
    #pragma unroll
    for (int off = 32; off > 0; off >>= 1) {
        ls += __shfl_down(ls, off);
        lss += __shfl_down(lss, off);
    }
    const int wid = tid >> 6;
    if ((tid & 63) == 0) { red[wid * 2] = ls; red[wid * 2 + 1] = lss; }
    __syncthreads();
    if (tid == 0) {
        float ts = 0.f, tss = 0.f;
        for (int w = 0; w < 4; ++w) { ts += red[w * 2]; tss += red[w * 2 + 1]; }
        const float mu = ts / (float)DD;
        const float var = tss / (float)DD - mu * mu;
        stats[0] = mu;
        stats[1] = rsqrtf(var + EPS);
    }
    __syncthreads();
    const float mu = stats[0], rsig = stats[1];
    const float o0 = (v0 - mu) * rsig * gamma[tid] + beta[tid];
    const float o1 = (v1 - mu) * rsig * gamma[tid + 256] + beta[tid + 256];
    out[row * DD + tid] = fmaxf(o0, 0.f);
    out[row * DD + tid + 256] = fmaxf(o1, 0.f);
}

// ---------------------------------------------------------------------------
extern "C" void kernel_launch(void* const* d_in, const int* in_sizes, int n_in,
                              void* d_out, int out_size, void* d_ws, size_t ws_size,
                              hipStream_t stream)
{
    const float* x    = (const float*)d_in[0];
    const int*   adj  = (const int*)  d_in[1];
    const float* e    = (const float*)d_in[2];
    const float* Wq   = (const float*)d_in[3];
    const float* Wkv  = (const float*)d_in[4];
    const float* We   = (const float*)d_in[5];
    const float* Wf   = (const float*)d_in[6];
    const float* bf   = (const float*)d_in[7];
    const float* gam  = (const float*)d_in[8];
    const float* bet  = (const float*)d_in[9];
    float* out = (float*)d_out;

    const int MROW = BB * LL;                    // 1024
    char* w = (char*)d_ws;
    unsigned short* Q_bf   = (unsigned short*)(w);                 // 1 MB (reused as attn_bf)
    unsigned short* KV_bf  = (unsigned short*)(w + (1u  << 20));   // 1 MB
    unsigned short* KVT_bf = (unsigned short*)(w + (2u  << 20));   // 1 MB
    float*          S1     = (float*)         (w + (3u  << 20));   // 4 MB
    unsigned short* T_bf   = (unsigned short*)(w + (7u  << 20));   // 1 MB
    unsigned short* P1     = (unsigned short*)(w + (8u  << 20));   // 2 MB
    unsigned short* G_bf   = (unsigned short*)(w + (10u << 20));   // 1 MB
    float*          vals   = (float*)         (w + (11u << 20));   // 2 MB
    unsigned short* xb     = (unsigned short*)(w + (13u << 20));   // 1 MB
    unsigned short* Wqkv_t = (unsigned short*)(w + (14u << 20));   // 1.5 MB (rows: Q|KV|M)
    unsigned short* Wf_t   = (unsigned short*)(w + (15u << 20) + (512u << 10)); // 0.5 MB
    unsigned short* We_bf  = (unsigned short*)(w + (16u << 20));   // 64 KB
    unsigned short* WeT_bf = (unsigned short*)(w + (16u << 20) + (64u << 10));  // 64 KB

    pack_all<<<1136, 256, 0, stream>>>(x, Wq, Wkv, Wf, We, xb, Wqkv_t, Wf_t, We_bf, WeT_bf);
    proj_gemm<<<dim3(24, 16), 256, 0, stream>>>(xb, Wqkv_t, Q_bf, KV_bf, KVT_bf, T_bf);
    qk_s1<<<512, 256, 0, stream>>>(Q_bf, KV_bf, S1);
    attn_fused<<<MROW, 256, 0, stream>>>(e, adj, S1, T_bf, P1, G_bf);
    // Q_bf is dead after qk_s1; reuse it as the attn output.
    pv_o2_gemm<<<256, 256, 0, stream>>>(P1, KVT_bf, G_bf, WeT_bf, (unsigned short*)Q_bf);
    ffn_gemm<<<dim3(8, 32), 256, 0, stream>>>((unsigned short*)Q_bf, Wf_t, bf, vals);
    ln_kernel<<<MROW, 256, 0, stream>>>(vals, gam, bet, out);
}